// Round 1
// baseline (313.981 us; speedup 1.0000x reference)
//
#include <hip/hip_runtime.h>
#include <math.h>

#define HDIM 1536
#define NUM_HEADS 12
#define NUM_KV 2
#define HEAD_DIM 128
#define GQA_REP 6
#define MAX_CACHE 131072
#define SCALE 0.08838834764831845f   // 128^-0.5

// workspace layout (float offsets)
#define WS_Q    0                     // 1536 floats (pre-scaled q)
#define WS_OUT  2048                  // 1536 floats (attention out, flat)
#define WS_L2   4096                  // 12*32*132 = 50688 floats
#define WS_PART 65536                 // 2048*6*132 = 1622016 floats
#define REC 132                       // per-partial record: [m, l, pad, pad, acc(128)]

#define UNITS_PER_G 1024              // 131072 / 128 positions per wave-unit
#define NEG_BIG (-1.0e30f)
#define MASK_NEG (-1.0e38f)

// ---------------------------------------------------------------------------
// Kernel 1: fused QKV projection. 2048 rows, one row per wave.
// rows [0,1536): q (scaled), rows [1536,1792): k -> cache, [1792,2048): v -> cache
// ---------------------------------------------------------------------------
__global__ __launch_bounds__(256) void proj_qkv(
    const float* __restrict__ x, const float* __restrict__ Wq,
    const float* __restrict__ Wk, const float* __restrict__ Wv,
    float* __restrict__ kv_k, float* __restrict__ kv_v,
    const int* __restrict__ pos_p, float* __restrict__ ws)
{
    int r    = (blockIdx.x * 256 + threadIdx.x) >> 6;   // 0..2047
    int lane = threadIdx.x & 63;

    const float* Wrow;
    if (r < HDIM)            Wrow = Wq + (size_t)r * HDIM;
    else if (r < HDIM + 256) Wrow = Wk + (size_t)(r - HDIM) * HDIM;
    else                     Wrow = Wv + (size_t)(r - HDIM - 256) * HDIM;

    const float4* w4 = (const float4*)Wrow;
    const float4* x4 = (const float4*)x;
    float sum = 0.f;
#pragma unroll
    for (int it = 0; it < 6; ++it) {
        float4 a = w4[lane + 64 * it];
        float4 b = x4[lane + 64 * it];
        sum += a.x * b.x + a.y * b.y + a.z * b.z + a.w * b.w;
    }
#pragma unroll
    for (int off = 32; off >= 1; off >>= 1) sum += __shfl_xor(sum, off);

    if (lane == 0) {
        if (r < HDIM) {
            ws[WS_Q + r] = sum * SCALE;
        } else {
            int pos = *pos_p;
            if (r < HDIM + 256) {
                int j = r - HDIM; int g = j >> 7, d = j & 127;
                kv_k[((size_t)g * MAX_CACHE + pos) * HEAD_DIM + d] = sum;
            } else {
                int j = r - HDIM - 256; int g = j >> 7, d = j & 127;
                kv_v[((size_t)g * MAX_CACHE + pos) * HEAD_DIM + d] = sum;
            }
        }
    }
}

// ---------------------------------------------------------------------------
// Kernel 2: flash-decode. One wave handles 128 positions of one KV group.
// Lanes split into two halves: half h handles position 2*i+h each iteration.
// Lane j (0..31 within half) holds dims 4j..4j+3 (float4).
// Per-wave partial record per head: [m, l, _, _, acc(128)].
// ---------------------------------------------------------------------------
__global__ __launch_bounds__(256) void attn_decode(
    const float* __restrict__ kv_k, const float* __restrict__ kv_v,
    const int* __restrict__ pos_p, float* __restrict__ ws)
{
    int wv   = (blockIdx.x * 256 + threadIdx.x) >> 6;   // 0..2047
    int lane = threadIdx.x & 63;
    int g = wv >> 10;            // kv group
    int u = wv & 1023;           // unit within group
    int h = lane >> 5;           // half (position parity)
    int j = lane & 31;           // float4 index within head_dim

    int seq_len = *pos_p + 1;
    if (seq_len > MAX_CACHE) seq_len = MAX_CACHE;

    // q fragments (pre-scaled)
    const float* qb = ws + WS_Q + g * (GQA_REP * HEAD_DIM);
    float4 q[GQA_REP];
#pragma unroll
    for (int r = 0; r < GQA_REP; ++r)
        q[r] = ((const float4*)(qb + r * HEAD_DIM))[j];

    float  m[GQA_REP], l[GQA_REP];
    float4 acc[GQA_REP];
#pragma unroll
    for (int r = 0; r < GQA_REP; ++r) {
        m[r] = NEG_BIG; l[r] = 0.f;
        acc[r].x = acc[r].y = acc[r].z = acc[r].w = 0.f;
    }

    int base = u * 128;
    const float4* Kb = (const float4*)(kv_k + ((size_t)g * MAX_CACHE + base) * HEAD_DIM);
    const float4* Vb = (const float4*)(kv_v + ((size_t)g * MAX_CACHE + base) * HEAD_DIM);
    int idx = h * 32 + j;        // float4 index for (2i+h) at i=0

    float4 Kc = Kb[idx];
    float4 Vc = Vb[idx];

    for (int i = 0; i < 64; ++i) {
        float4 Kn, Vn;
        if (i < 63) {            // register prefetch of next iteration
            Kn = Kb[idx + (i + 1) * 64];
            Vn = Vb[idx + (i + 1) * 64];
        }
        int p = base + 2 * i + h;
        float maskadd = (p < seq_len) ? 0.f : MASK_NEG;

        float s[GQA_REP];
#pragma unroll
        for (int r = 0; r < GQA_REP; ++r) {
            float sr = Kc.x * q[r].x + Kc.y * q[r].y + Kc.z * q[r].z + Kc.w * q[r].w;
#pragma unroll
            for (int off = 16; off >= 1; off >>= 1) sr += __shfl_xor(sr, off);
            s[r] = sr + maskadd;
        }
#pragma unroll
        for (int r = 0; r < GQA_REP; ++r) {
            float mn    = fmaxf(m[r], s[r]);
            float alpha = __expf(m[r] - mn);
            float pw    = __expf(s[r] - mn);
            l[r] = l[r] * alpha + pw;
            acc[r].x = acc[r].x * alpha + pw * Vc.x;
            acc[r].y = acc[r].y * alpha + pw * Vc.y;
            acc[r].z = acc[r].z * alpha + pw * Vc.z;
            acc[r].w = acc[r].w * alpha + pw * Vc.w;
            m[r] = mn;
        }
        Kc = Kn; Vc = Vn;
    }

    // merge the two halves (symmetric computation, both halves produce same result)
#pragma unroll
    for (int r = 0; r < GQA_REP; ++r) {
        float mo = __shfl_xor(m[r], 32);
        float lo = __shfl_xor(l[r], 32);
        float4 ao;
        ao.x = __shfl_xor(acc[r].x, 32);
        ao.y = __shfl_xor(acc[r].y, 32);
        ao.z = __shfl_xor(acc[r].z, 32);
        ao.w = __shfl_xor(acc[r].w, 32);
        float M  = fmaxf(m[r], mo);
        float a0 = __expf(m[r] - M);
        float a1 = __expf(mo   - M);
        float L  = l[r] * a0 + lo * a1;
        float4 A;
        A.x = acc[r].x * a0 + ao.x * a1;
        A.y = acc[r].y * a0 + ao.y * a1;
        A.z = acc[r].z * a0 + ao.z * a1;
        A.w = acc[r].w * a0 + ao.w * a1;

        float* rec = ws + WS_PART + ((size_t)(g * UNITS_PER_G + u) * GQA_REP + r) * REC;
        if (lane < 32) ((float4*)(rec + 4))[j] = A;
        if (lane == 0) { rec[0] = M; rec[1] = L; }
    }
}

// ---------------------------------------------------------------------------
// Kernel 3: combine stage 1 — 12 heads x 32 slabs; each block merges 32 units.
// Single wave per block.
// ---------------------------------------------------------------------------
__global__ __launch_bounds__(64) void combine1(float* __restrict__ ws)
{
    int b  = blockIdx.x;          // 0..383
    int hh = b >> 5;              // head 0..11
    int s  = b & 31;              // slab
    int g = hh / GQA_REP, r = hh % GQA_REP;
    int t  = threadIdx.x;         // 0..63
    int um = t & 31;

    const float* base = ws + WS_PART +
        ((size_t)(g * UNITS_PER_G + s * 32) * GQA_REP + r) * REC;
    const float* rec = base + (size_t)um * GQA_REP * REC;
    float mu = rec[0], lu = rec[1];

    float M = mu;
#pragma unroll
    for (int off = 16; off >= 1; off >>= 1) M = fmaxf(M, __shfl_xor(M, off));
    float w = __expf(mu - M);
    float L = lu * w;
#pragma unroll
    for (int off = 16; off >= 1; off >>= 1) L += __shfl_xor(L, off);

    float2 a; a.x = 0.f; a.y = 0.f;      // dims 2t, 2t+1
    for (int uu = 0; uu < 32; ++uu) {
        float wu = __shfl(w, uu);
        float2 av = ((const float2*)(base + (size_t)uu * GQA_REP * REC + 4))[t];
        a.x += wu * av.x;
        a.y += wu * av.y;
    }
    float* orec = ws + WS_L2 + (size_t)(hh * 32 + s) * REC;
    ((float2*)(orec + 4))[t] = a;
    if (t == 0) { orec[0] = M; orec[1] = L; }
}

// ---------------------------------------------------------------------------
// Kernel 4: combine stage 2 — 12 heads; merge 32 slab records, write out vec.
// ---------------------------------------------------------------------------
__global__ __launch_bounds__(64) void combine2(float* __restrict__ ws)
{
    int hh = blockIdx.x;          // 0..11
    int t  = threadIdx.x;
    int um = t & 31;

    const float* base = ws + WS_L2 + (size_t)(hh * 32) * REC;
    const float* rec  = base + (size_t)um * REC;
    float mu = rec[0], lu = rec[1];

    float M = mu;
#pragma unroll
    for (int off = 16; off >= 1; off >>= 1) M = fmaxf(M, __shfl_xor(M, off));
    float w = __expf(mu - M);
    float L = lu * w;
#pragma unroll
    for (int off = 16; off >= 1; off >>= 1) L += __shfl_xor(L, off);

    float2 a; a.x = 0.f; a.y = 0.f;
    for (int uu = 0; uu < 32; ++uu) {
        float wu = __shfl(w, uu);
        float2 av = ((const float2*)(base + (size_t)uu * REC + 4))[t];
        a.x += wu * av.x;
        a.y += wu * av.y;
    }
    float invL = 1.f / L;
    ws[WS_OUT + hh * HEAD_DIM + 2 * t]     = a.x * invL;
    ws[WS_OUT + hh * HEAD_DIM + 2 * t + 1] = a.y * invL;
}

// ---------------------------------------------------------------------------
// Kernel 5: output projection y = Wo @ out. One row per wave.
// ---------------------------------------------------------------------------
__global__ __launch_bounds__(256) void proj_out(
    const float* __restrict__ Wo, const float* __restrict__ ws,
    float* __restrict__ y)
{
    int r    = (blockIdx.x * 256 + threadIdx.x) >> 6;   // 0..1535
    int lane = threadIdx.x & 63;
    const float4* w4 = (const float4*)(Wo + (size_t)r * HDIM);
    const float4* o4 = (const float4*)(ws + WS_OUT);
    float sum = 0.f;
#pragma unroll
    for (int it = 0; it < 6; ++it) {
        float4 a = w4[lane + 64 * it];
        float4 b = o4[lane + 64 * it];
        sum += a.x * b.x + a.y * b.y + a.z * b.z + a.w * b.w;
    }
#pragma unroll
    for (int off = 32; off >= 1; off >>= 1) sum += __shfl_xor(sum, off);
    if (lane == 0) y[r] = sum;
}

// ---------------------------------------------------------------------------
extern "C" void kernel_launch(void* const* d_in, const int* in_sizes, int n_in,
                              void* d_out, int out_size, void* d_ws, size_t ws_size,
                              hipStream_t stream) {
    const float* x   = (const float*)d_in[0];
    const float* Wq  = (const float*)d_in[1];
    const float* Wk  = (const float*)d_in[2];
    const float* Wv  = (const float*)d_in[3];
    const float* Wo  = (const float*)d_in[4];
    float*       kvk = (float*)d_in[5];
    float*       kvv = (float*)d_in[6];
    const int*   pos = (const int*)d_in[7];
    float* ws = (float*)d_ws;
    float* y  = (float*)d_out;

    proj_qkv   <<<512, 256, 0, stream>>>(x, Wq, Wk, Wv, kvk, kvv, pos, ws);
    attn_decode<<<512, 256, 0, stream>>>(kvk, kvv, pos, ws);
    combine1   <<<384,  64, 0, stream>>>(ws);
    combine2   <<< 12,  64, 0, stream>>>(ws);
    proj_out   <<<384, 256, 0, stream>>>(Wo, ws, y);
}